// Round 4
// baseline (1728.117 us; speedup 1.0000x reference)
//
#include <hip/hip_runtime.h>
#include <stdint.h>

#define B_ 8
#define L_ 2048
#define D_ 1024
#define Z_ 128
#define H_ 2048
#define NE_ 16
#define G_ 32
#define MAXPOS_ 2048
#define NMX_ 4224  // D + Z + H + D (u | q,k | r | hx)
#define EPS_ 1e-5f
#define PC_ 2.0f
#define NTILE_ 16            // L/128 q-tiles
#define NPACK_ 136           // 16*17/2 packed causal tiles
#define TILE_ELEMS_ 16384    // 128*128

typedef short bf16x8 __attribute__((ext_vector_type(8)));
typedef float f32x4 __attribute__((ext_vector_type(4)));

__device__ __forceinline__ float bf2f(uint16_t u) {
  union { uint32_t u; float f; } v; v.u = ((uint32_t)u) << 16; return v.f;
}
__device__ __forceinline__ uint16_t f2bf(float f) {
  union { float f; uint32_t u; } v; v.f = f;
  uint32_t r = (v.u + 0x7FFFu + ((v.u >> 16) & 1u)) >> 16;
  return (uint16_t)r;
}
__device__ __forceinline__ float sigmoidf_(float x) { return 1.f / (1.f + __expf(-x)); }
__device__ __forceinline__ float siluf_(float x) { return x / (1.f + __expf(-x)); }

__device__ __forceinline__ float waveRedSum(float v) {
  #pragma unroll
  for (int m = 32; m; m >>= 1) v += __shfl_xor(v, m, 64);
  return v;
}

// async global->LDS, 16 bytes per lane; lds dst must be waveBase + lane*16
__device__ __forceinline__ void gl2lds(const uint16_t* g, uint16_t* l) {
  __builtin_amdgcn_global_load_lds(
      (const __attribute__((address_space(1))) void*)g,
      (__attribute__((address_space(3))) void*)l, 16, 0, 0);
}

// ---------------- fallback when workspace too small ----------------
__global__ __launch_bounds__(256) void k_fallback(float* __restrict__ out, int n, float wsmb) {
  for (int i = blockIdx.x * 256 + threadIdx.x; i < n; i += gridDim.x * 256)
    out[i] = (i == 0) ? wsmb : 0.f;
}

// ---------------- fp32 -> bf16 conversion (weights) ----------------
__global__ __launch_bounds__(256) void k_f2bf(const float* __restrict__ src,
                                              uint16_t* __restrict__ dst, int n) {
  for (int i = blockIdx.x * 256 + threadIdx.x; i < n; i += gridDim.x * 256)
    dst[i] = f2bf(src[i]);
}

// ---------------- TimestepNorm: causal cumulative group norm ----------------
__global__ __launch_bounds__(256) void k_tnorm(const float* __restrict__ x,
                                               const float* __restrict__ pm,
                                               const float* __restrict__ plv,
                                               const float* __restrict__ w,
                                               const float* __restrict__ bias,
                                               uint16_t* __restrict__ xn) {
  __shared__ float s1[L_];
  __shared__ float s2[L_];
  const int b = blockIdx.x / G_;
  const int g = blockIdx.x % G_;
  const int tid = threadIdx.x;
  const int j = tid & 31;
  const int lsub = tid >> 5;

  for (int basei = 0; basei < L_; basei += 8) {
    const int l = basei + lsub;
    float v = x[((size_t)(b * L_ + l)) * D_ + g * 32 + j];
    float a = v, sq = v * v;
    #pragma unroll
    for (int m = 1; m <= 16; m <<= 1) { a += __shfl_xor(a, m, 64); sq += __shfl_xor(sq, m, 64); }
    if (j == 0) { s1[l] = a; s2[l] = sq; }
  }
  __syncthreads();

  if (tid < 64) {
    const int lane = tid;
    #pragma unroll
    for (int pass = 0; pass < 2; ++pass) {
      float* s = pass ? s2 : s1;
      const int b0 = lane * 32;
      float tot = 0.f;
      for (int t = 0; t < 32; ++t) tot += s[b0 + t];
      float incl = tot;
      #pragma unroll
      for (int off = 1; off < 64; off <<= 1) {
        float nv = __shfl_up(incl, off, 64);
        if (lane >= off) incl += nv;
      }
      float run = incl - tot;
      for (int t = 0; t < 32; ++t) { run += s[b0 + t]; s[b0 + t] = run; }
    }
  }
  __syncthreads();

  const float pmv = pm[g];
  const float pvv = __expf(plv[g]);
  const float wj = w[g * 32 + j];
  const float bj = bias[g * 32 + j];
  const float pterm = PC_ * (pvv + pmv * pmv);
  for (int basei = 0; basei < L_; basei += 8) {
    const int l = basei + lsub;
    const size_t idx = ((size_t)(b * L_ + l)) * D_ + g * 32 + j;
    float v = x[idx];
    float cnt = PC_ + 32.f * (float)(l + 1);
    float mean = (PC_ * pmv + s1[l]) / cnt;
    float var = (pterm + s2[l]) / cnt - mean * mean;
    float o = (v - mean) * rsqrtf(var + EPS_) * wj + bj;
    xn[idx] = f2bf(o);
  }
}

// ---------------- generic 32x32-tiled transpose, batched over z ----------------
template <typename T>
__global__ __launch_bounds__(256) void k_transpose(const T* __restrict__ src,
                                                   T* __restrict__ dst, int R, int C) {
  __shared__ T tile[32][33];
  const size_t batch = (size_t)R * C * blockIdx.z;
  const int c0 = blockIdx.x * 32, r0 = blockIdx.y * 32;
  const int tx = threadIdx.x & 31, ty = threadIdx.x >> 5;
  #pragma unroll
  for (int k = 0; k < 4; ++k) {
    int r = ty + k * 8;
    tile[r][tx] = src[batch + (size_t)(r0 + r) * C + c0 + tx];
  }
  __syncthreads();
  #pragma unroll
  for (int k = 0; k < 4; ++k) {
    int r = ty + k * 8;
    dst[batch + (size_t)(c0 + r) * R + r0 + tx] = tile[tx][r];
  }
}

// ---------------- MultiHeadEMA via chunked linear recurrence ----------------
__global__ __launch_bounds__(64) void k_ema(const uint16_t* __restrict__ xnT,
                                            const float* __restrict__ delta,
                                            const float* __restrict__ alpha,
                                            const float* __restrict__ beta,
                                            const float* __restrict__ gamma,
                                            const float* __restrict__ omega,
                                            float* __restrict__ mxT) {
  __shared__ float hst[64 * NE_];
  const int bd = blockIdx.x;
  const int d = bd & (D_ - 1);
  const int c = threadIdx.x;

  float q[NE_], pb[NE_], gs[NE_];
  #pragma unroll
  for (int n = 0; n < NE_; ++n) {
    float p = sigmoidf_(delta[d * NE_ + n]);
    float a = sigmoidf_(alpha[d * NE_ + n]);
    q[n] = 1.f - p * a;
    pb[n] = p * beta[d * NE_ + n];
    gs[n] = gamma[d * NE_ + n] * 0.25f;
  }

  const uint16_t* xp = xnT + (size_t)bd * L_ + c * 32;
  float h[NE_];
  #pragma unroll
  for (int n = 0; n < NE_; ++n) h[n] = 0.f;

  for (int k = 0; k < 32; ++k) {
    float xv = bf2f(xp[k]);
    #pragma unroll
    for (int n = 0; n < NE_; ++n) h[n] = fmaf(q[n], h[n], pb[n] * xv);
  }
  #pragma unroll
  for (int n = 0; n < NE_; ++n) hst[c * NE_ + n] = h[n];
  __syncthreads();

  if (c < NE_) {
    float p = sigmoidf_(delta[d * NE_ + c]);
    float a = sigmoidf_(alpha[d * NE_ + c]);
    float qq = 1.f - p * a;
    float q32 = qq * qq; q32 *= q32; q32 *= q32; q32 *= q32; q32 *= q32;
    float hi = 0.f;
    for (int cc = 0; cc < 64; ++cc) {
      float cur = hst[cc * NE_ + c];
      hst[cc * NE_ + c] = hi;
      hi = fmaf(q32, hi, cur);
    }
  }
  __syncthreads();

  #pragma unroll
  for (int n = 0; n < NE_; ++n) h[n] = hst[c * NE_ + n];
  const float om = omega[d];
  float* op = mxT + (size_t)bd * L_ + c * 32;
  for (int k = 0; k < 32; ++k) {
    float xv = bf2f(xp[k]);
    float accv = 0.f;
    #pragma unroll
    for (int n = 0; n < NE_; ++n) {
      h[n] = fmaf(q[n], h[n], pb[n] * xv);
      accv = fmaf(gs[n], h[n], accv);
    }
    op[k] = accv + om * xv;
  }
}

// ---------------- RMS norm over D ----------------
__global__ __launch_bounds__(256) void k_rms(const float* __restrict__ mx,
                                             const float* __restrict__ w,
                                             uint16_t* __restrict__ mxn) {
  __shared__ float red[4];
  const size_t row = blockIdx.x;
  const int tid = threadIdx.x;
  float ss = 0.f;
  #pragma unroll
  for (int i = 0; i < 4; ++i) {
    float v = mx[row * D_ + tid + i * 256];
    ss += v * v;
  }
  ss = waveRedSum(ss);
  if ((tid & 63) == 0) red[tid >> 6] = ss;
  __syncthreads();
  ss = red[0] + red[1] + red[2] + red[3];
  const float scale = rsqrtf(ss * (1.f / D_) + EPS_);
  #pragma unroll
  for (int i = 0; i < 4; ++i) {
    int dcol = tid + i * 256;
    mxn[row * D_ + dcol] = f2bf(mx[row * D_ + dcol] * scale * w[dcol]);
  }
}

// ---- MFMA GEMM (m97 structure): C = A(MxK) @ B(NxK)^T, fused epilogues ----
// MODE 0: V     out = silu(acc + bv[col])               -> bf16 v
// MODE 1: BASE  acc + bmx[col], split u(bf16)/q,k(bf16)/r(bf16)/hx(f32)
// MODE 4: WH    g=silu(acc+hx); out = x + u*(g-x)        -> f32 d_out
template <int MODE>
__global__ __launch_bounds__(256) void k_gemm(
    const uint16_t* __restrict__ A, const uint16_t* __restrict__ Bm,
    int N, int K,
    const float* __restrict__ bias,
    float* __restrict__ outf, uint16_t* __restrict__ outb,
    uint16_t* __restrict__ ubuf, uint16_t* __restrict__ qbuf,
    uint16_t* __restrict__ kbuf, uint16_t* __restrict__ rbuf,
    float* __restrict__ hxbuf,
    const float* __restrict__ qg, const float* __restrict__ qbt,
    const float* __restrict__ x0) {
  const int bm = blockIdx.x * 128;
  const int bn = blockIdx.y * 128;
  __shared__ uint16_t As[128 * 32];
  __shared__ uint16_t Bs[128 * 32];
  const int tid = threadIdx.x;
  const int wave = tid >> 6, lane = tid & 63;
  const int quad = lane >> 4, r16 = lane & 15;
  const int wm = wave >> 1, wn = wave & 1;
  const int rowW = wm * 64, colW = wn * 64;

  f32x4 acc[4][4];
  const f32x4 zf = {0.f, 0.f, 0.f, 0.f};
  #pragma unroll
  for (int i = 0; i < 4; ++i)
    #pragma unroll
    for (int j = 0; j < 4; ++j) acc[i][j] = zf;

  const int rA = tid >> 2;
  const int sg = (tid & 3) * 8;
  const uint16_t* gA0 = A + (size_t)(bm + rA) * K + sg;
  const uint16_t* gA1 = A + (size_t)(bm + 64 + rA) * K + sg;
  const uint16_t* gB0 = Bm + (size_t)(bn + rA) * K + sg;
  const uint16_t* gB1 = Bm + (size_t)(bn + 64 + rA) * K + sg;
  uint16_t* lA0 = As + tid * 8;
  uint16_t* lA1 = As + 2048 + tid * 8;
  uint16_t* lB0 = Bs + tid * 8;
  uint16_t* lB1 = Bs + 2048 + tid * 8;

  for (int kb = 0; kb < K; kb += 32) {
    __syncthreads();
    gl2lds(gA0 + kb, lA0);
    gl2lds(gA1 + kb, lA1);
    gl2lds(gB0 + kb, lB0);
    gl2lds(gB1 + kb, lB1);
    __syncthreads();
    bf16x8 af[4], bfr[4];
    #pragma unroll
    for (int i = 0; i < 4; ++i)
      af[i] = *(const bf16x8*)&As[(rowW + i * 16 + r16) * 32 + quad * 8];
    #pragma unroll
    for (int j = 0; j < 4; ++j)
      bfr[j] = *(const bf16x8*)&Bs[(colW + j * 16 + r16) * 32 + quad * 8];
    #pragma unroll
    for (int i = 0; i < 4; ++i)
      #pragma unroll
      for (int j = 0; j < 4; ++j)
        acc[i][j] = __builtin_amdgcn_mfma_f32_16x16x32_bf16(af[i], bfr[j], acc[i][j], 0, 0, 0);
  }

  #pragma unroll
  for (int i = 0; i < 4; ++i) {
    #pragma unroll
    for (int j = 0; j < 4; ++j) {
      #pragma unroll
      for (int r = 0; r < 4; ++r) {
        const int row = bm + rowW + i * 16 + quad * 4 + r;
        const int col = bn + colW + j * 16 + r16;
        float val = acc[i][j][r];
        if (MODE == 0) {
          outb[(size_t)row * N + col] = f2bf(siluf_(val + bias[col]));
        } else if (MODE == 1) {
          val += bias[col];
          if (col < D_) {
            ubuf[(size_t)row * D_ + col] = f2bf(sigmoidf_(val));
          } else if (col < D_ + Z_) {
            const int zc = col - D_;
            const float zr = siluf_(val);
            qbuf[(size_t)row * Z_ + zc] =
                f2bf((zr * qg[zc] + qbt[zc]) * 0.08838834764831845f);
            kbuf[(size_t)row * Z_ + zc] = f2bf(zr * qg[Z_ + zc] + qbt[Z_ + zc]);
          } else if (col < D_ + Z_ + H_) {
            rbuf[(size_t)row * H_ + (col - D_ - Z_)] = f2bf(siluf_(val));
          } else {
            hxbuf[(size_t)row * D_ + (col - D_ - Z_ - H_)] = val;
          }
        } else {
          const size_t idx = (size_t)row * N + col;
          float g = siluf_(val + hxbuf[idx]);   // read hx (d_out) ...
          float xv = x0[idx];
          outf[idx] = xv + bf2f(ubuf[idx]) * (g - xv);  // ... then write same addr
        }
      }
    }
  }
}

// ---- fused QK^T + rel_bias + causal softmax -> packed-triangular P (bf16) ----
// two-phase flash: pass1 online (m,l) stats, pass2 recompute S, write P.
// grid: (qt = L/128, bl = batches in group); block 256 (4 waves x 32 q-rows)
__global__ __launch_bounds__(256) void k_qksm(
    const uint16_t* __restrict__ qg, const uint16_t* __restrict__ kg,
    const float* __restrict__ relb, uint16_t* __restrict__ Pp) {
  __shared__ uint16_t Ks[128 * 128];
  __shared__ float relwin[256];
  const int qt = blockIdx.x;
  const int bl = blockIdx.y;
  const int tid = threadIdx.x;
  const int w = tid >> 6, lane = tid & 63;
  const int quad = lane >> 4, r16 = lane & 15;
  const uint16_t* qb_b = qg + (size_t)bl * L_ * Z_;
  const uint16_t* kb_b = kg + (size_t)bl * L_ * Z_;
  uint16_t* P_b = Pp + (size_t)bl * NPACK_ * TILE_ELEMS_;

  // Q fragments, register-resident for the whole block
  bf16x8 aq[2][4];
  #pragma unroll
  for (int i = 0; i < 2; ++i)
    #pragma unroll
    for (int s = 0; s < 4; ++s)
      aq[i][s] = *(const bf16x8*)&qb_b[(size_t)(qt * 128 + w * 32 + i * 16 + r16) * Z_ +
                                       s * 32 + quad * 8];

  float m8[8], l8[8];
  #pragma unroll
  for (int t = 0; t < 8; ++t) { m8[t] = -3.4e38f; l8[t] = 0.f; }

  const f32x4 zf = {0.f, 0.f, 0.f, 0.f};

  // ---- phase 1: stats ----
  for (int kt = 0; kt <= qt; ++kt) {
    __syncthreads();
    const uint16_t* src = kb_b + (size_t)kt * 128 * Z_;
    #pragma unroll
    for (int s2 = 0; s2 < 8; ++s2)
      gl2lds(src + s2 * 2048 + tid * 8, Ks + s2 * 2048 + tid * 8);
    if (tid < 255) relwin[tid] = relb[2047 + (kt - qt) * 128 - 127 + tid];
    __syncthreads();
    #pragma unroll
    for (int j = 0; j < 8; ++j) {
      f32x4 a0 = zf, a1 = zf;
      #pragma unroll
      for (int s = 0; s < 4; ++s) {
        bf16x8 bk = *(const bf16x8*)&Ks[(j * 16 + r16) * 128 + s * 32 + quad * 8];
        a0 = __builtin_amdgcn_mfma_f32_16x16x32_bf16(aq[0][s], bk, a0, 0, 0, 0);
        a1 = __builtin_amdgcn_mfma_f32_16x16x32_bf16(aq[1][s], bk, a1, 0, 0, 0);
      }
      #pragma unroll
      for (int i = 0; i < 2; ++i) {
        const f32x4 av = i ? a1 : a0;
        #pragma unroll
        for (int r = 0; r < 4; ++r) {
          const int rloc = w * 32 + i * 16 + quad * 4 + r;
          const int cloc = j * 16 + r16;
          if (kt < qt || cloc <= rloc) {
            const float v = av[r] + relwin[cloc - rloc + 127];
            const int t = i * 4 + r;
            const float mn = fmaxf(m8[t], v);
            l8[t] = l8[t] * __expf(m8[t] - mn) + __expf(v - mn);
            m8[t] = mn;
          }
        }
      }
    }
  }

  // combine stats across the 16 column-lanes (same quad group)
  #pragma unroll
  for (int t = 0; t < 8; ++t) {
    #pragma unroll
    for (int msk = 1; msk <= 8; msk <<= 1) {
      const float mo = __shfl_xor(m8[t], msk, 64);
      const float lo = __shfl_xor(l8[t], msk, 64);
      const float mn = fmaxf(m8[t], mo);
      l8[t] = l8[t] * __expf(m8[t] - mn) + lo * __expf(mo - mn);
      m8[t] = mn;
    }
    l8[t] = 1.f / l8[t];
  }

  // ---- phase 2: recompute, normalize, write packed P ----
  for (int kt = 0; kt <= qt; ++kt) {
    __syncthreads();
    const uint16_t* src = kb_b + (size_t)kt * 128 * Z_;
    #pragma unroll
    for (int s2 = 0; s2 < 8; ++s2)
      gl2lds(src + s2 * 2048 + tid * 8, Ks + s2 * 2048 + tid * 8);
    if (tid < 255) relwin[tid] = relb[2047 + (kt - qt) * 128 - 127 + tid];
    __syncthreads();
    uint16_t* Pt = P_b + (size_t)(qt * (qt + 1) / 2 + kt) * TILE_ELEMS_;
    #pragma unroll
    for (int j = 0; j < 8; ++j) {
      f32x4 a0 = zf, a1 = zf;
      #pragma unroll
      for (int s = 0; s < 4; ++s) {
        bf16x8 bk = *(const bf16x8*)&Ks[(j * 16 + r16) * 128 + s * 32 + quad * 8];
        a0 = __builtin_amdgcn_mfma_f32_16x16x32_bf16(aq[0][s], bk, a0, 0, 0, 0);
        a1 = __builtin_amdgcn_mfma_f32_16x16x32_bf16(aq[1][s], bk, a1, 0, 0, 0);
      }
      #pragma unroll
      for (int i = 0; i < 2; ++i) {
        const f32x4 av = i ? a1 : a0;
        #pragma unroll
        for (int r = 0; r < 4; ++r) {
          const int rloc = w * 32 + i * 16 + quad * 4 + r;
          const int cloc = j * 16 + r16;
          const int t = i * 4 + r;
          float p = 0.f;
          if (kt < qt || cloc <= rloc) {
            const float v = av[r] + relwin[cloc - rloc + 127];
            p = __expf(v - m8[t]) * l8[t];
          }
          Pt[rloc * 128 + cloc] = f2bf(p);
        }
      }
    }
  }
}

// ---- PV GEMM: hr = (P @ V) * r, packed-triangular P, batched over z ----
// grid (qt, H/128, NB)
__global__ __launch_bounds__(256) void k_pv(
    const uint16_t* __restrict__ Pp, const uint16_t* __restrict__ vT,
    const uint16_t* __restrict__ rmul, uint16_t* __restrict__ hr) {
  __shared__ uint16_t As[128 * 32];
  __shared__ uint16_t Bs[128 * 32];
  const int qt = blockIdx.x;
  const int bn = blockIdx.y * 128;
  const int bl = blockIdx.z;
  const uint16_t* P_b = Pp + (size_t)bl * NPACK_ * TILE_ELEMS_;
  const uint16_t* v_b = vT + (size_t)bl * H_ * L_;
  const uint16_t* r_b = rmul + (size_t)bl * L_ * H_;
  uint16_t* h_b = hr + (size_t)bl * L_ * H_;

  const int tid = threadIdx.x;
  const int wave = tid >> 6, lane = tid & 63;
  const int quad = lane >> 4, r16 = lane & 15;
  const int wm = wave >> 1, wn = wave & 1;
  const int rowW = wm * 64, colW = wn * 64;

  f32x4 acc[4][4];
  const f32x4 zf = {0.f, 0.f, 0.f, 0.f};
  #pragma unroll
  for (int i = 0; i < 4; ++i)
    #pragma unroll
    for (int j = 0; j < 4; ++j) acc[i][j] = zf;

  const int rA = tid >> 2;
  const int sg = (tid & 3) * 8;
  uint16_t* lA0 = As + tid * 8;
  uint16_t* lA1 = As + 2048 + tid * 8;
  uint16_t* lB0 = Bs + tid * 8;
  uint16_t* lB1 = Bs + 2048 + tid * 8;

  for (int kt = 0; kt <= qt; ++kt) {
    const uint16_t* At = P_b + (size_t)(qt * (qt + 1) / 2 + kt) * TILE_ELEMS_;
    #pragma unroll
    for (int ks = 0; ks < 4; ++ks) {
      const int kb = kt * 128 + ks * 32;
      __syncthreads();
      gl2lds(At + rA * 128 + ks * 32 + sg, lA0);
      gl2lds(At + (rA + 64) * 128 + ks * 32 + sg, lA1);
      gl2lds(v_b + (size_t)(bn + rA) * L_ + kb + sg, lB0);
      gl2lds(v_b + (size_t)(bn + 64 + rA) * L_ + kb + sg, lB1);
      __syncthreads();
      bf16x8 af[4], bfr[4];
      #pragma unroll
      for (int i = 0; i < 4; ++i)
        af[i] = *(const bf16x8*)&As[(rowW + i * 16 + r16) * 32 + quad * 8];
      #pragma unroll
      for (int j = 0; j < 4; ++j)
        bfr[j] = *(const bf16x8*)&Bs[(colW + j * 16 + r16) * 32 + quad * 8];
      #pragma unroll
      for (int i = 0; i < 4; ++i)
        #pragma unroll
        for (int j = 0; j < 4; ++j)
          acc[i][j] = __builtin_amdgcn_mfma_f32_16x16x32_bf16(af[i], bfr[j], acc[i][j], 0, 0, 0);
    }
  }

  #pragma unroll
  for (int i = 0; i < 4; ++i) {
    #pragma unroll
    for (int j = 0; j < 4; ++j) {
      #pragma unroll
      for (int r = 0; r < 4; ++r) {
        const int row = qt * 128 + rowW + i * 16 + quad * 4 + r;
        const int col = bn + colW + j * 16 + r16;
        const size_t idx = (size_t)row * H_ + col;
        h_b[idx] = f2bf(acc[i][j][r] * bf2f(r_b[idx]));
      }
    }
  }
}

extern "C" void kernel_launch(void* const* d_in, const int* in_sizes, int n_in,
                              void* d_out, int out_size, void* d_ws, size_t ws_size,
                              hipStream_t stream) {
  (void)in_sizes; (void)n_in;
  const float* x         = (const float*)d_in[0];
  const float* prior_mean= (const float*)d_in[1];
  const float* prior_logv= (const float*)d_in[2];
  const float* tn_w      = (const float*)d_in[3];
  const float* tn_b      = (const float*)d_in[4];
  const float* delta     = (const float*)d_in[5];
  const float* alpha     = (const float*)d_in[6];
  const float* ema_beta  = (const float*)d_in[7];
  const float* ema_gamma = (const float*)d_in[8];
  const float* omega     = (const float*)d_in[9];
  const float* rms_w     = (const float*)d_in[10];
  const float* Wv        = (const float*)d_in[11];
  const float* bv        = (const float*)d_in[12];
  const float* Wmx       = (const float*)d_in[13];
  const float* bmx       = (const float*)d_in[14];
  const float* Wh        = (const float*)d_in[15];
  const float* qk_gamma  = (const float*)d_in[16];
  const float* qk_beta   = (const float*)d_in[17];
  const float* rel_bias  = (const float*)d_in[18];
  float* out = (float*)d_out;

  const int BL = B_ * L_;
  const size_t MB = 1024 * 1024;
  const size_t REQUIRED = 256 * MB;

  if (ws_size < REQUIRED) {
    k_fallback<<<dim3(4096), dim3(256), 0, stream>>>(out, out_size, (float)(ws_size / MB));
    return;
  }

  char* p = (char*)d_ws;
  // [0,32): u (bf16)                      BASE -> WH
  uint16_t* ubuf  = (uint16_t*)(p);
  // [32,36): qb (bf16)                    BASE -> QKsm   | later wh_b
  uint16_t* qb    = (uint16_t*)(p + 32 * MB);
  uint16_t* wh_b  = (uint16_t*)(p + 32 * MB);
  // [36,40): kb (bf16)                    BASE -> QKsm
  uint16_t* kb2   = (uint16_t*)(p + 36 * MB);
  // [40,58): Ppack (bf16, 4 batches)      QKsm -> PV     | earlier wv_b, wmx_b
  uint16_t* Ppack = (uint16_t*)(p + 40 * MB);
  uint16_t* wv_b  = (uint16_t*)(p + 40 * MB);
  uint16_t* wmx_b = (uint16_t*)(p + 40 * MB);
  // [64,128): vbuf -> mx(f32) -> r (bf16)
  uint16_t* vbuf  = (uint16_t*)(p + 64 * MB);
  float*    mx    = (float*)   (p + 64 * MB);
  uint16_t* rbuf  = (uint16_t*)(p + 64 * MB);
  // [128,192): vT (bf16)                  VGEMM -> PV
  uint16_t* vT    = (uint16_t*)(p + 128 * MB);
  // [192,256): xn -> (xnT,mxn in upper half) -> hr
  uint16_t* xn    = (uint16_t*)(p + 192 * MB);
  uint16_t* xnT   = (uint16_t*)(p + 224 * MB);
  uint16_t* mxn   = (uint16_t*)(p + 224 * MB);
  uint16_t* hr    = (uint16_t*)(p + 192 * MB);
  // d_out doubles as: mxT f32 (EMA out) -> hx f32 (BASE out) -> out
  float* mxT = out;
  float* hx  = out;

  // 1. Wv -> bf16
  k_f2bf<<<dim3(1024), dim3(256), 0, stream>>>(Wv, wv_b, H_ * D_);
  // 2. timestep norm -> xn
  k_tnorm<<<dim3(B_ * G_), dim3(256), 0, stream>>>(x, prior_mean, prior_logv, tn_w, tn_b, xn);
  // 3. xn -> xnT
  k_transpose<uint16_t><<<dim3(D_ / 32, L_ / 32, B_), dim3(256), 0, stream>>>(xn, xnT, L_, D_);
  // 4. v = silu(xn @ Wv^T + bv) -> vbuf
  k_gemm<0><<<dim3(BL / 128, H_ / 128), dim3(256), 0, stream>>>(
      xn, wv_b, H_, D_, bv, nullptr, vbuf,
      nullptr, nullptr, nullptr, nullptr, nullptr, nullptr, nullptr, nullptr);
  // 5. v -> vT
  k_transpose<uint16_t><<<dim3(H_ / 32, L_ / 32, B_), dim3(256), 0, stream>>>(vbuf, vT, L_, H_);
  // 6. EMA: xnT -> mxT (d_out)
  k_ema<<<dim3(B_ * D_), dim3(64), 0, stream>>>(xnT, delta, alpha, ema_beta, ema_gamma, omega, mxT);
  // 7. mxT -> mx
  k_transpose<float><<<dim3(L_ / 32, D_ / 32, B_), dim3(256), 0, stream>>>(mxT, mx, D_, L_);
  // 8. RMS norm -> mxn
  k_rms<<<dim3(BL), dim3(256), 0, stream>>>(mx, rms_w, mxn);
  // 9. Wmx -> bf16
  k_f2bf<<<dim3(2048), dim3(256), 0, stream>>>(Wmx, wmx_b, NMX_ * D_);
  // 10. base GEMM -> u, q, k, r, hx
  k_gemm<1><<<dim3(BL / 128, NMX_ / 128), dim3(256), 0, stream>>>(
      mxn, wmx_b, NMX_, D_, bmx, nullptr, nullptr,
      ubuf, qb, kb2, rbuf, hx, qk_gamma, qk_beta, nullptr);
  // 11. attention in 2 groups of 4 batches
  const int NB = 4;
  for (int g = 0; g < B_ / NB; ++g) {
    const size_t zoff = (size_t)g * NB * L_ * Z_;
    const size_t hoff = (size_t)g * NB * L_ * H_;
    k_qksm<<<dim3(NTILE_, NB), dim3(256), 0, stream>>>(
        qb + zoff, kb2 + zoff, rel_bias, Ppack);
    k_pv<<<dim3(NTILE_, H_ / 128, NB), dim3(256), 0, stream>>>(
        Ppack, vT + hoff, rbuf + hoff, hr + hoff);
  }
  // 12. Wh -> bf16 (over dead qb)
  k_f2bf<<<dim3(1024), dim3(256), 0, stream>>>(Wh, wh_b, D_ * H_);
  // 13. final: g = silu(hx + hr@Wh^T); out = x + u*(g-x)
  k_gemm<4><<<dim3(BL / 128, D_ / 128), dim3(256), 0, stream>>>(
      hr, wh_b, D_, H_, nullptr, out, nullptr,
      ubuf, nullptr, nullptr, nullptr, hx, nullptr, nullptr, x);
}

// Round 5
// 1320.323 us; speedup vs baseline: 1.3089x; 1.3089x over previous
//
#include <hip/hip_runtime.h>
#include <stdint.h>

#define B_ 8
#define L_ 2048
#define D_ 1024
#define Z_ 128
#define H_ 2048
#define NE_ 16
#define G_ 32
#define MAXPOS_ 2048
#define NMX_ 4224  // D + Z + H + D (u | z | r | hx)
#define EPS_ 1e-5f
#define PC_ 2.0f
#define NTILE_ 16            // L/128 q-tiles
#define NPACK_ 136           // 16*17/2 packed causal tiles
#define TILE_ELEMS_ 16384    // 128*128

typedef short bf16x8 __attribute__((ext_vector_type(8)));
typedef float f32x4 __attribute__((ext_vector_type(4)));

__device__ __forceinline__ float bf2f(uint16_t u) {
  union { uint32_t u; float f; } v; v.u = ((uint32_t)u) << 16; return v.f;
}
__device__ __forceinline__ uint16_t f2bf(float f) {
  union { float f; uint32_t u; } v; v.f = f;
  uint32_t r = (v.u + 0x7FFFu + ((v.u >> 16) & 1u)) >> 16;
  return (uint16_t)r;
}
__device__ __forceinline__ float sigmoidf_(float x) { return 1.f / (1.f + __expf(-x)); }
__device__ __forceinline__ float siluf_(float x) { return x / (1.f + __expf(-x)); }

__device__ __forceinline__ float waveRedSum(float v) {
  #pragma unroll
  for (int m = 32; m; m >>= 1) v += __shfl_xor(v, m, 64);
  return v;
}

// async global->LDS, 16 bytes per lane; lds dst must be waveBase + lane*16
__device__ __forceinline__ void gl2lds(const uint16_t* g, uint16_t* l) {
  __builtin_amdgcn_global_load_lds(
      (const __attribute__((address_space(1))) void*)g,
      (__attribute__((address_space(3))) void*)l, 16, 0, 0);
}

// ---------------- fallback when workspace too small ----------------
__global__ __launch_bounds__(256) void k_fallback(float* __restrict__ out, int n, float wsmb) {
  for (int i = blockIdx.x * 256 + threadIdx.x; i < n; i += gridDim.x * 256)
    out[i] = (i == 0) ? wsmb : 0.f;
}

// ---------------- fp32 -> bf16 conversion (weights) ----------------
__global__ __launch_bounds__(256) void k_f2bf(const float* __restrict__ src,
                                              uint16_t* __restrict__ dst, int n) {
  for (int i = blockIdx.x * 256 + threadIdx.x; i < n; i += gridDim.x * 256)
    dst[i] = f2bf(src[i]);
}

// ---------------- TimestepNorm, parallel 3-phase ----------------
// phase A: per-l group sums. grid (B*G, 16), block 256
__global__ __launch_bounds__(256) void k_tnsum(const float* __restrict__ x,
                                               float* __restrict__ s1g,
                                               float* __restrict__ s2g) {
  const int bg = blockIdx.x;
  const int b = bg / G_, g = bg % G_;
  const int tid = threadIdx.x;
  const int j = tid & 31;
  const int lsub = tid >> 5;
  #pragma unroll
  for (int i = 0; i < 16; ++i) {
    const int l = blockIdx.y * 128 + i * 8 + lsub;
    float v = x[((size_t)(b * L_ + l)) * D_ + g * 32 + j];
    float a = v, sq = v * v;
    #pragma unroll
    for (int m = 1; m <= 16; m <<= 1) { a += __shfl_xor(a, m, 64); sq += __shfl_xor(sq, m, 64); }
    if (j == 0) { s1g[(size_t)bg * L_ + l] = a; s2g[(size_t)bg * L_ + l] = sq; }
  }
}

// phase B: inclusive cumsum over L per (b,g). grid 256, block 64
__global__ __launch_bounds__(64) void k_tnscan(float* __restrict__ s1g,
                                               float* __restrict__ s2g) {
  const int bg = blockIdx.x;
  const int lane = threadIdx.x;
  #pragma unroll
  for (int pass = 0; pass < 2; ++pass) {
    float* gp = (pass ? s2g : s1g) + (size_t)bg * L_;
    float loc[32];
    const int b0 = lane * 32;
    float tot = 0.f;
    #pragma unroll
    for (int t = 0; t < 32; ++t) { loc[t] = gp[b0 + t]; tot += loc[t]; }
    float incl = tot;
    #pragma unroll
    for (int off = 1; off < 64; off <<= 1) {
      float nv = __shfl_up(incl, off, 64);
      if (lane >= off) incl += nv;
    }
    float run = incl - tot;
    #pragma unroll
    for (int t = 0; t < 32; ++t) { run += loc[t]; gp[b0 + t] = run; }
  }
}

// phase C: normalize. grid (B*G, 16), block 256
__global__ __launch_bounds__(256) void k_tnnorm(const float* __restrict__ x,
                                                const float* __restrict__ s1g,
                                                const float* __restrict__ s2g,
                                                const float* __restrict__ pm,
                                                const float* __restrict__ plv,
                                                const float* __restrict__ w,
                                                const float* __restrict__ bias,
                                                uint16_t* __restrict__ xn) {
  const int bg = blockIdx.x;
  const int b = bg / G_, g = bg % G_;
  const int tid = threadIdx.x;
  const int j = tid & 31;
  const int lsub = tid >> 5;
  const float pmv = pm[g];
  const float pvv = __expf(plv[g]);
  const float wj = w[g * 32 + j];
  const float bj = bias[g * 32 + j];
  const float pterm = PC_ * (pvv + pmv * pmv);
  #pragma unroll
  for (int i = 0; i < 16; ++i) {
    const int l = blockIdx.y * 128 + i * 8 + lsub;
    const size_t idx = ((size_t)(b * L_ + l)) * D_ + g * 32 + j;
    const float v = x[idx];
    const float cnt = PC_ + 32.f * (float)(l + 1);
    const float mean = (PC_ * pmv + s1g[(size_t)bg * L_ + l]) / cnt;
    const float var = (pterm + s2g[(size_t)bg * L_ + l]) / cnt - mean * mean;
    xn[idx] = f2bf((v - mean) * rsqrtf(var + EPS_) * wj + bj);
  }
}

// ---------------- generic 32x32-tiled transpose, batched over z ----------------
template <typename T>
__global__ __launch_bounds__(256) void k_transpose(const T* __restrict__ src,
                                                   T* __restrict__ dst, int R, int C) {
  __shared__ T tile[32][33];
  const size_t batch = (size_t)R * C * blockIdx.z;
  const int c0 = blockIdx.x * 32, r0 = blockIdx.y * 32;
  const int tx = threadIdx.x & 31, ty = threadIdx.x >> 5;
  #pragma unroll
  for (int k = 0; k < 4; ++k) {
    int r = ty + k * 8;
    tile[r][tx] = src[batch + (size_t)(r0 + r) * C + c0 + tx];
  }
  __syncthreads();
  #pragma unroll
  for (int k = 0; k < 4; ++k) {
    int r = ty + k * 8;
    dst[batch + (size_t)(c0 + r) * R + r0 + tx] = tile[tx][r];
  }
}

// ---------------- MultiHeadEMA via chunked linear recurrence ----------------
__global__ __launch_bounds__(64) void k_ema(const uint16_t* __restrict__ xnT,
                                            const float* __restrict__ delta,
                                            const float* __restrict__ alpha,
                                            const float* __restrict__ beta,
                                            const float* __restrict__ gamma,
                                            const float* __restrict__ omega,
                                            float* __restrict__ mxT) {
  __shared__ float hst[64 * NE_];
  const int bd = blockIdx.x;
  const int d = bd & (D_ - 1);
  const int c = threadIdx.x;

  float q[NE_], pb[NE_], gs[NE_];
  #pragma unroll
  for (int n = 0; n < NE_; ++n) {
    float p = sigmoidf_(delta[d * NE_ + n]);
    float a = sigmoidf_(alpha[d * NE_ + n]);
    q[n] = 1.f - p * a;
    pb[n] = p * beta[d * NE_ + n];
    gs[n] = gamma[d * NE_ + n] * 0.25f;
  }

  const uint16_t* xp = xnT + (size_t)bd * L_ + c * 32;
  bf16x8 xin[4];
  #pragma unroll
  for (int s = 0; s < 4; ++s) xin[s] = *(const bf16x8*)(xp + s * 8);

  float h[NE_];
  #pragma unroll
  for (int n = 0; n < NE_; ++n) h[n] = 0.f;

  #pragma unroll
  for (int k = 0; k < 32; ++k) {
    float xv = bf2f((uint16_t)xin[k >> 3][k & 7]);
    #pragma unroll
    for (int n = 0; n < NE_; ++n) h[n] = fmaf(q[n], h[n], pb[n] * xv);
  }
  #pragma unroll
  for (int n = 0; n < NE_; ++n) hst[c * NE_ + n] = h[n];
  __syncthreads();

  if (c < NE_) {
    float qq = q[c];
    float q32 = qq * qq; q32 *= q32; q32 *= q32; q32 *= q32; q32 *= q32;  // q^32
    float hi = 0.f;
    for (int cc = 0; cc < 64; ++cc) {
      float cur = hst[cc * NE_ + c];
      hst[cc * NE_ + c] = hi;
      hi = fmaf(q32, hi, cur);
    }
  }
  __syncthreads();

  #pragma unroll
  for (int n = 0; n < NE_; ++n) h[n] = hst[c * NE_ + n];
  const float om = omega[d];
  float* op = mxT + (size_t)bd * L_ + c * 32;
  f32x4 ov;
  #pragma unroll
  for (int k = 0; k < 32; ++k) {
    float xv = bf2f((uint16_t)xin[k >> 3][k & 7]);
    float accv = 0.f;
    #pragma unroll
    for (int n = 0; n < NE_; ++n) {
      h[n] = fmaf(q[n], h[n], pb[n] * xv);
      accv = fmaf(gs[n], h[n], accv);
    }
    ov[k & 3] = accv + om * xv;
    if ((k & 3) == 3) *(f32x4*)(op + (k & ~3)) = ov;
  }
}

// ---------------- RMS norm over D ----------------
__global__ __launch_bounds__(256) void k_rms(const float* __restrict__ mx,
                                             const float* __restrict__ w,
                                             uint16_t* __restrict__ mxn) {
  __shared__ float red[4];
  const size_t row = blockIdx.x;
  const int tid = threadIdx.x;
  float ss = 0.f;
  #pragma unroll
  for (int i = 0; i < 4; ++i) {
    float v = mx[row * D_ + tid + i * 256];
    ss += v * v;
  }
  ss = waveRedSum(ss);
  if ((tid & 63) == 0) red[tid >> 6] = ss;
  __syncthreads();
  ss = red[0] + red[1] + red[2] + red[3];
  const float scale = rsqrtf(ss * (1.f / D_) + EPS_);
  #pragma unroll
  for (int i = 0; i < 4; ++i) {
    int dcol = tid + i * 256;
    mxn[row * D_ + dcol] = f2bf(mx[row * D_ + dcol] * scale * w[dcol]);
  }
}

// ---------------- q/k prep from z ----------------
__global__ __launch_bounds__(256) void k_qkprep(const float* __restrict__ z,
                                                const float* __restrict__ qg,
                                                const float* __restrict__ qb,
                                                uint16_t* __restrict__ q,
                                                uint16_t* __restrict__ k, int n) {
  for (int i = blockIdx.x * 256 + threadIdx.x; i < n; i += gridDim.x * 256) {
    int zc = i & (Z_ - 1);
    float v = z[i];
    q[i] = f2bf((v * qg[zc] + qb[zc]) * 0.08838834764831845f);
    k[i] = f2bf(v * qg[Z_ + zc] + qb[Z_ + zc]);
  }
}

// ---- MFMA GEMM (m97 structure): C = A(MxK) @ B(NxK)^T, fused epilogues ----
// MODE 0: V     out = silu(acc + bv[col])               -> bf16 v
// MODE 1: BASE  acc + bmx[col], split u(bf16)/z(f32)/r(bf16)/hx(f32)
// MODE 4: WH    g=silu(acc+hx); out = x + u*(g-x)        -> f32 d_out
template <int MODE>
__global__ __launch_bounds__(256) void k_gemm(
    const uint16_t* __restrict__ A, const uint16_t* __restrict__ Bm,
    int N, int K,
    const float* __restrict__ bias,
    float* __restrict__ outf, uint16_t* __restrict__ outb,
    uint16_t* __restrict__ ubuf, float* __restrict__ zbuf,
    uint16_t* __restrict__ rbuf, float* __restrict__ hxbuf,
    const float* __restrict__ x0) {
  const int bm = blockIdx.x * 128;
  const int bn = blockIdx.y * 128;
  __shared__ uint16_t As[128 * 32];
  __shared__ uint16_t Bs[128 * 32];
  const int tid = threadIdx.x;
  const int wave = tid >> 6, lane = tid & 63;
  const int quad = lane >> 4, r16 = lane & 15;
  const int wm = wave >> 1, wn = wave & 1;
  const int rowW = wm * 64, colW = wn * 64;

  f32x4 acc[4][4];
  const f32x4 zf = {0.f, 0.f, 0.f, 0.f};
  #pragma unroll
  for (int i = 0; i < 4; ++i)
    #pragma unroll
    for (int j = 0; j < 4; ++j) acc[i][j] = zf;

  const int rA = tid >> 2;
  const int sg = (tid & 3) * 8;
  const uint16_t* gA0 = A + (size_t)(bm + rA) * K + sg;
  const uint16_t* gA1 = A + (size_t)(bm + 64 + rA) * K + sg;
  const uint16_t* gB0 = Bm + (size_t)(bn + rA) * K + sg;
  const uint16_t* gB1 = Bm + (size_t)(bn + 64 + rA) * K + sg;
  uint16_t* lA0 = As + tid * 8;
  uint16_t* lA1 = As + 2048 + tid * 8;
  uint16_t* lB0 = Bs + tid * 8;
  uint16_t* lB1 = Bs + 2048 + tid * 8;

  for (int kb = 0; kb < K; kb += 32) {
    __syncthreads();
    gl2lds(gA0 + kb, lA0);
    gl2lds(gA1 + kb, lA1);
    gl2lds(gB0 + kb, lB0);
    gl2lds(gB1 + kb, lB1);
    __syncthreads();
    bf16x8 af[4], bfr[4];
    #pragma unroll
    for (int i = 0; i < 4; ++i)
      af[i] = *(const bf16x8*)&As[(rowW + i * 16 + r16) * 32 + quad * 8];
    #pragma unroll
    for (int j = 0; j < 4; ++j)
      bfr[j] = *(const bf16x8*)&Bs[(colW + j * 16 + r16) * 32 + quad * 8];
    #pragma unroll
    for (int i = 0; i < 4; ++i)
      #pragma unroll
      for (int j = 0; j < 4; ++j)
        acc[i][j] = __builtin_amdgcn_mfma_f32_16x16x32_bf16(af[i], bfr[j], acc[i][j], 0, 0, 0);
  }

  #pragma unroll
  for (int i = 0; i < 4; ++i) {
    #pragma unroll
    for (int j = 0; j < 4; ++j) {
      #pragma unroll
      for (int r = 0; r < 4; ++r) {
        const int row = bm + rowW + i * 16 + quad * 4 + r;
        const int col = bn + colW + j * 16 + r16;
        float val = acc[i][j][r];
        if (MODE == 0) {
          outb[(size_t)row * N + col] = f2bf(siluf_(val + bias[col]));
        } else if (MODE == 1) {
          val += bias[col];
          if (col < D_)                 ubuf[(size_t)row * D_ + col] = f2bf(sigmoidf_(val));
          else if (col < D_ + Z_)       zbuf[(size_t)row * Z_ + (col - D_)] = siluf_(val);
          else if (col < D_ + Z_ + H_)  rbuf[(size_t)row * H_ + (col - D_ - Z_)] = f2bf(siluf_(val));
          else                          hxbuf[(size_t)row * D_ + (col - D_ - Z_ - H_)] = val;
        } else {
          const size_t idx = (size_t)row * N + col;
          float g = siluf_(val + hxbuf[idx]);   // read hx (d_out) ...
          float xv = x0[idx];
          outf[idx] = xv + bf2f(ubuf[idx]) * (g - xv);  // ... then write same addr
        }
      }
    }
  }
}

// ---- fused QK^T + rel_bias + causal softmax -> packed-triangular P (bf16) ----
// two-phase flash: pass1 online (m,l) stats, pass2 recompute S, write P.
// grid: (qt = L/128, B); block 256 (4 waves x 32 q-rows)
__global__ __launch_bounds__(256) void k_qksm(
    const uint16_t* __restrict__ qg, const uint16_t* __restrict__ kg,
    const float* __restrict__ relb, uint16_t* __restrict__ Pp) {
  __shared__ uint16_t Ks[128 * 128];
  __shared__ float relwin[256];
  const int qt = blockIdx.x;
  const int bl = blockIdx.y;
  const int tid = threadIdx.x;
  const int w = tid >> 6, lane = tid & 63;
  const int quad = lane >> 4, r16 = lane & 15;
  const uint16_t* qb_b = qg + (size_t)bl * L_ * Z_;
  const uint16_t* kb_b = kg + (size_t)bl * L_ * Z_;
  uint16_t* P_b = Pp + (size_t)bl * NPACK_ * TILE_ELEMS_;

  // Q fragments, register-resident for the whole block
  bf16x8 aq[2][4];
  #pragma unroll
  for (int i = 0; i < 2; ++i)
    #pragma unroll
    for (int s = 0; s < 4; ++s)
      aq[i][s] = *(const bf16x8*)&qb_b[(size_t)(qt * 128 + w * 32 + i * 16 + r16) * Z_ +
                                       s * 32 + quad * 8];

  float m8[8], l8[8];
  #pragma unroll
  for (int t = 0; t < 8; ++t) { m8[t] = -3.4e38f; l8[t] = 0.f; }

  const f32x4 zf = {0.f, 0.f, 0.f, 0.f};

  // ---- phase 1: stats ----
  for (int kt = 0; kt <= qt; ++kt) {
    __syncthreads();
    const uint16_t* src = kb_b + (size_t)kt * 128 * Z_;
    #pragma unroll
    for (int s2 = 0; s2 < 8; ++s2)
      gl2lds(src + s2 * 2048 + tid * 8, Ks + s2 * 2048 + tid * 8);
    if (tid < 255) relwin[tid] = relb[2047 + (kt - qt) * 128 - 127 + tid];
    __syncthreads();
    #pragma unroll
    for (int j = 0; j < 8; ++j) {
      f32x4 a0 = zf, a1 = zf;
      #pragma unroll
      for (int s = 0; s < 4; ++s) {
        bf16x8 bk = *(const bf16x8*)&Ks[(j * 16 + r16) * 128 + s * 32 + quad * 8];
        a0 = __builtin_amdgcn_mfma_f32_16x16x32_bf16(aq[0][s], bk, a0, 0, 0, 0);
        a1 = __builtin_amdgcn_mfma_f32_16x16x32_bf16(aq[1][s], bk, a1, 0, 0, 0);
      }
      #pragma unroll
      for (int i = 0; i < 2; ++i) {
        const f32x4 av = i ? a1 : a0;
        #pragma unroll
        for (int r = 0; r < 4; ++r) {
          const int rloc = w * 32 + i * 16 + quad * 4 + r;
          const int cloc = j * 16 + r16;
          if (kt < qt || cloc <= rloc) {
            const float v = av[r] + relwin[cloc - rloc + 127];
            const int t = i * 4 + r;
            const float mn = fmaxf(m8[t], v);
            l8[t] = l8[t] * __expf(m8[t] - mn) + __expf(v - mn);
            m8[t] = mn;
          }
        }
      }
    }
  }

  // combine stats across the 16 column-lanes (same quad group)
  #pragma unroll
  for (int t = 0; t < 8; ++t) {
    #pragma unroll
    for (int msk = 1; msk <= 8; msk <<= 1) {
      const float mo = __shfl_xor(m8[t], msk, 64);
      const float lo = __shfl_xor(l8[t], msk, 64);
      const float mn = fmaxf(m8[t], mo);
      l8[t] = l8[t] * __expf(m8[t] - mn) + lo * __expf(mo - mn);
      m8[t] = mn;
    }
    l8[t] = 1.f / l8[t];
  }

  // ---- phase 2: recompute, normalize, write packed P ----
  for (int kt = 0; kt <= qt; ++kt) {
    __syncthreads();
    const uint16_t* src = kb_b + (size_t)kt * 128 * Z_;
    #pragma unroll
    for (int s2 = 0; s2 < 8; ++s2)
      gl2lds(src + s2 * 2048 + tid * 8, Ks + s2 * 2048 + tid * 8);
    if (tid < 255) relwin[tid] = relb[2047 + (kt - qt) * 128 - 127 + tid];
    __syncthreads();
    uint16_t* Pt = P_b + (size_t)(qt * (qt + 1) / 2 + kt) * TILE_ELEMS_;
    #pragma unroll
    for (int j = 0; j < 8; ++j) {
      f32x4 a0 = zf, a1 = zf;
      #pragma unroll
      for (int s = 0; s < 4; ++s) {
        bf16x8 bk = *(const bf16x8*)&Ks[(j * 16 + r16) * 128 + s * 32 + quad * 8];
        a0 = __builtin_amdgcn_mfma_f32_16x16x32_bf16(aq[0][s], bk, a0, 0, 0, 0);
        a1 = __builtin_amdgcn_mfma_f32_16x16x32_bf16(aq[1][s], bk, a1, 0, 0, 0);
      }
      #pragma unroll
      for (int i = 0; i < 2; ++i) {
        const f32x4 av = i ? a1 : a0;
        #pragma unroll
        for (int r = 0; r < 4; ++r) {
          const int rloc = w * 32 + i * 16 + quad * 4 + r;
          const int cloc = j * 16 + r16;
          const int t = i * 4 + r;
          float p = 0.f;
          if (kt < qt || cloc <= rloc) {
            const float v = av[r] + relwin[cloc - rloc + 127];
            p = __expf(v - m8[t]) * l8[t];
          }
          Pt[rloc * 128 + cloc] = f2bf(p);
        }
      }
    }
  }
}

// ---- PV GEMM: hr = (P @ V) * r, packed-triangular P, in-place over r ----
// grid (qt, H/128, B)
__global__ __launch_bounds__(256) void k_pv(
    const uint16_t* __restrict__ Pp, const uint16_t* __restrict__ vT,
    uint16_t* __restrict__ rh) {
  __shared__ uint16_t As[128 * 32];
  __shared__ uint16_t Bs[128 * 32];
  const int qt = blockIdx.x;
  const int bn = blockIdx.y * 128;
  const int bl = blockIdx.z;
  const uint16_t* P_b = Pp + (size_t)bl * NPACK_ * TILE_ELEMS_;
  const uint16_t* v_b = vT + (size_t)bl * H_ * L_;
  uint16_t* rh_b = rh + (size_t)bl * L_ * H_;

  const int tid = threadIdx.x;
  const int wave = tid >> 6, lane = tid & 63;
  const int quad = lane >> 4, r16 = lane & 15;
  const int wm = wave >> 1, wn = wave & 1;
  const int rowW = wm * 64, colW = wn * 64;

  f32x4 acc[4][4];
  const f32x4 zf = {0.f, 0.f, 0.f, 0.f};
  #pragma unroll
  for (int i = 0; i < 4; ++i)
    #pragma unroll
    for (int j = 0; j < 4; ++j) acc[i][j] = zf;

  const int rA = tid >> 2;
  const int sg = (tid & 3) * 8;
  uint16_t* lA0 = As + tid * 8;
  uint16_t* lA1 = As + 2048 + tid * 8;
  uint16_t* lB0 = Bs + tid * 8;
  uint16_t* lB1 = Bs + 2048 + tid * 8;

  for (int kt = 0; kt <= qt; ++kt) {
    const uint16_t* At = P_b + (size_t)(qt * (qt + 1) / 2 + kt) * TILE_ELEMS_;
    #pragma unroll
    for (int ks = 0; ks < 4; ++ks) {
      const int kb = kt * 128 + ks * 32;
      __syncthreads();
      gl2lds(At + rA * 128 + ks * 32 + sg, lA0);
      gl2lds(At + (rA + 64) * 128 + ks * 32 + sg, lA1);
      gl2lds(v_b + (size_t)(bn + rA) * L_ + kb + sg, lB0);
      gl2lds(v_b + (size_t)(bn + 64 + rA) * L_ + kb + sg, lB1);
      __syncthreads();
      bf16x8 af[4], bfr[4];
      #pragma unroll
      for (int i = 0; i < 4; ++i)
        af[i] = *(const bf16x8*)&As[(rowW + i * 16 + r16) * 32 + quad * 8];
      #pragma unroll
      for (int j = 0; j < 4; ++j)
        bfr[j] = *(const bf16x8*)&Bs[(colW + j * 16 + r16) * 32 + quad * 8];
      #pragma unroll
      for (int i = 0; i < 4; ++i)
        #pragma unroll
        for (int j = 0; j < 4; ++j)
          acc[i][j] = __builtin_amdgcn_mfma_f32_16x16x32_bf16(af[i], bfr[j], acc[i][j], 0, 0, 0);
    }
  }

  #pragma unroll
  for (int i = 0; i < 4; ++i) {
    #pragma unroll
    for (int j = 0; j < 4; ++j) {
      #pragma unroll
      for (int r = 0; r < 4; ++r) {
        const int row = qt * 128 + rowW + i * 16 + quad * 4 + r;
        const int col = bn + colW + j * 16 + r16;
        const size_t idx = (size_t)row * H_ + col;
        const float rv = bf2f(rh_b[idx]);         // read r ...
        rh_b[idx] = f2bf(acc[i][j][r] * rv);      // ... then overwrite (same thread)
      }
    }
  }
}

extern "C" void kernel_launch(void* const* d_in, const int* in_sizes, int n_in,
                              void* d_out, int out_size, void* d_ws, size_t ws_size,
                              hipStream_t stream) {
  (void)in_sizes; (void)n_in;
  const float* x         = (const float*)d_in[0];
  const float* prior_mean= (const float*)d_in[1];
  const float* prior_logv= (const float*)d_in[2];
  const float* tn_w      = (const float*)d_in[3];
  const float* tn_b      = (const float*)d_in[4];
  const float* delta     = (const float*)d_in[5];
  const float* alpha     = (const float*)d_in[6];
  const float* ema_beta  = (const float*)d_in[7];
  const float* ema_gamma = (const float*)d_in[8];
  const float* omega     = (const float*)d_in[9];
  const float* rms_w     = (const float*)d_in[10];
  const float* Wv        = (const float*)d_in[11];
  const float* bv        = (const float*)d_in[12];
  const float* Wmx       = (const float*)d_in[13];
  const float* bmx       = (const float*)d_in[14];
  const float* Wh        = (const float*)d_in[15];
  const float* qk_gamma  = (const float*)d_in[16];
  const float* qk_beta   = (const float*)d_in[17];
  const float* rel_bias  = (const float*)d_in[18];
  float* out = (float*)d_out;

  const int BL = B_ * L_;
  const size_t MB = 1024 * 1024;
  const size_t REQUIRED = 256 * MB;

  if (ws_size < REQUIRED) {
    k_fallback<<<dim3(4096), dim3(256), 0, stream>>>(out, out_size, (float)(ws_size / MB));
    return;
  }

  char* p = (char*)d_ws;
  // A [0,32): xn (bf16) -> ubuf (bf16)
  uint16_t* xn   = (uint16_t*)(p);
  uint16_t* ubuf = (uint16_t*)(p);
  // B [32,64): s1s2 (4MB, tnorm only) -> xnT -> mxn
  float*    s1g  = (float*)   (p + 32 * MB);
  float*    s2g  = (float*)   (p + 34 * MB);
  uint16_t* xnT  = (uint16_t*)(p + 32 * MB);
  uint16_t* mxn  = (uint16_t*)(p + 32 * MB);
  // C [64,128): vbuf -> mx (f32) -> rbuf/hr (in-place PV)
  uint16_t* vbuf = (uint16_t*)(p + 64 * MB);
  float*    mx   = (float*)   (p + 64 * MB);
  uint16_t* rbuf = (uint16_t*)(p + 64 * MB);
  // D [128,192): wv_b -> vT
  uint16_t* wv_b = (uint16_t*)(p + 128 * MB);
  uint16_t* vT   = (uint16_t*)(p + 128 * MB);
  // E [192,256): wmx_b(9) | z(8) | qb(4) | kb(4) | Ppack(35.65); wh_b over dead wmx_b
  uint16_t* wmx_b = (uint16_t*)(p + 192 * MB);
  uint16_t* wh_b  = (uint16_t*)(p + 192 * MB);
  float*    zb    = (float*)   (p + 201 * MB);
  uint16_t* qb    = (uint16_t*)(p + 209 * MB);
  uint16_t* kb2   = (uint16_t*)(p + 213 * MB);
  uint16_t* Ppack = (uint16_t*)(p + 217 * MB);
  // d_out doubles as: mxT f32 (EMA out) -> hx f32 (BASE out) -> out
  float* mxT = out;
  float* hx  = out;

  // 1. weights -> bf16 (Wv into D, Wmx into E; both regions dead until use)
  k_f2bf<<<dim3(1024), dim3(256), 0, stream>>>(Wv, wv_b, H_ * D_);
  k_f2bf<<<dim3(2048), dim3(256), 0, stream>>>(Wmx, wmx_b, NMX_ * D_);
  // 2. timestep norm (3-phase parallel) -> xn
  k_tnsum<<<dim3(B_ * G_, 16), dim3(256), 0, stream>>>(x, s1g, s2g);
  k_tnscan<<<dim3(B_ * G_), dim3(64), 0, stream>>>(s1g, s2g);
  k_tnnorm<<<dim3(B_ * G_, 16), dim3(256), 0, stream>>>(
      x, s1g, s2g, prior_mean, prior_logv, tn_w, tn_b, xn);
  // 3. xn -> xnT (overwrites dead s1s2)
  k_transpose<uint16_t><<<dim3(D_ / 32, L_ / 32, B_), dim3(256), 0, stream>>>(xn, xnT, L_, D_);
  // 4. v = silu(xn @ Wv^T + bv) -> vbuf
  k_gemm<0><<<dim3(BL / 128, H_ / 128), dim3(256), 0, stream>>>(
      xn, wv_b, H_, D_, bv, nullptr, vbuf,
      nullptr, nullptr, nullptr, nullptr, nullptr);
  // 5. v -> vT (overwrites dead wv_b)
  k_transpose<uint16_t><<<dim3(H_ / 32, L_ / 32, B_), dim3(256), 0, stream>>>(vbuf, vT, L_, H_);
  // 6. EMA: xnT -> mxT (d_out)
  k_ema<<<dim3(B_ * D_), dim3(64), 0, stream>>>(xnT, delta, alpha, ema_beta, ema_gamma, omega, mxT);
  // 7. mxT -> mx (overwrites dead vbuf)
  k_transpose<float><<<dim3(L_ / 32, D_ / 32, B_), dim3(256), 0, stream>>>(mxT, mx, D_, L_);
  // 8. RMS norm -> mxn (overwrites dead xnT)
  k_rms<<<dim3(BL), dim3(256), 0, stream>>>(mx, rms_w, mxn);
  // 9. BASE GEMM -> u(A), z(E), r(C), hx(d_out)
  k_gemm<1><<<dim3(BL / 128, NMX_ / 128), dim3(256), 0, stream>>>(
      mxn, wmx_b, NMX_, D_, bmx, nullptr, nullptr,
      ubuf, zb, rbuf, hx, nullptr);
  // 10. q,k from z
  k_qkprep<<<dim3(1024), dim3(256), 0, stream>>>(zb, qk_gamma, qk_beta, qb, kb2, BL * Z_);
  // 11. fused QK+softmax -> packed P (all 8 batches, one dispatch)
  k_qksm<<<dim3(NTILE_, B_), dim3(256), 0, stream>>>(qb, kb2, rel_bias, Ppack);
  // 12. PV GEMM, hr = (P@V)*r in-place over rbuf (one dispatch)
  k_pv<<<dim3(NTILE_, H_ / 128, B_), dim3(256), 0, stream>>>(Ppack, vT, rbuf);
  // 13. Wh -> bf16 (over dead wmx_b)
  k_f2bf<<<dim3(1024), dim3(256), 0, stream>>>(Wh, wh_b, D_ * H_);
  // 14. final: g = silu(hx + hr@Wh^T); out = x + u*(g-x)
  k_gemm<4><<<dim3(BL / 128, D_ / 128), dim3(256), 0, stream>>>(
      rbuf, wh_b, D_, H_, nullptr, out, nullptr,
      ubuf, nullptr, nullptr, hx, x);
}